// Round 4
// baseline (194.657 us; speedup 1.0000x reference)
//
#include <hip/hip_runtime.h>

// Problem constants (from reference)
#define KSIZE   32
#define KSTRIDE 16
#define HK      4
#define HD      128
#define ROW     (HK * HD)                       // 512 floats per token
#define ROW4    (ROW / 4)                       // 128 float4 per token
#define BATCH   4
#define SEQLEN  16384
#define CHUNKS_PER_BATCH ((SEQLEN - KSIZE) / KSTRIDE + 1)   // 1023
#define TOTAL_CHUNKS     (BATCH * CHUNKS_PER_BATCH)         // 4092

// SPAN=8 sequential-span (byte-minimal: 147 MB read, same as round 3), but
// staging each 32KB half-window via global_load_lds DMA into double-buffered
// LDS. Rounds 0-3 showed effective BW tracks waves/CU because per-wave
// in-flight loads are VGPR-capped (~9 float4/lane => 4.0 TB/s at 4 w/CU).
// DMA keeps a full 32KB half-window in flight per block (64KB/CU with the
// 2 resident blocks) -- in-flight demand no longer depends on wave count.
#define SPAN 8
#define BLOCKS_PER_BATCH ((CHUNKS_PER_BATCH + SPAN - 1) / SPAN)  // 128
#define TOTAL_BLOCKS     (BATCH * BLOCKS_PER_BATCH)              // 512
#define HWBYTES (KSTRIDE * ROW * 4)             // 32768 B per half-window

typedef const void __attribute__((address_space(1))) GAS;
typedef void __attribute__((address_space(3)))       LAS;

__global__ __launch_bounds__(128)
void compress_k_fused(const float* __restrict__ k,
                      const int* __restrict__ cu_seqlens,
                      float* __restrict__ out,
                      float* __restrict__ tail) {
    __shared__ float4 buf[2][KSTRIDE * ROW4];   // 2 x 32 KiB = 64 KiB

    const int blk = blockIdx.x;
    const int b   = blk / BLOCKS_PER_BATCH;
    const int cb  = blk - b * BLOCKS_PER_BATCH;
    const int c0  = cb * SPAN;                               // first chunk
    const int gc  = (CHUNKS_PER_BATCH - c0 < SPAN) ? (CHUNKS_PER_BATCH - c0)
                                                   : SPAN;   // 8, or 7 (last)

    const int t    = threadIdx.x;               // 0..127
    const int w    = t >> 6;                    // wave id (uniform per wave)
    const int lane = t & 63;

    const char* gbase = (const char*)(k +
        ((long)cu_seqlens[b] + (long)c0 * KSTRIDE) * ROW);

    // DMA half-window j (32KB, contiguous in global) into buf[sel].
    // LDS dest must be wave-uniform + lane*16: each wave copies its 16KB
    // half as 16 x 1KB segments (lane*16 only on the GLOBAL address).
    auto stage = [&](int sel, int j) {
        const char* g = gbase + (size_t)j * HWBYTES + (size_t)w * (HWBYTES / 2)
                        + (size_t)lane * 16;
        char* l = (char*)&buf[sel][0] + (size_t)w * (HWBYTES / 2);
        #pragma unroll
        for (int i = 0; i < 16; ++i)
            __builtin_amdgcn_global_load_lds((GAS*)(g + i * 1024),
                                             (LAS*)(l + i * 1024), 16, 0, 0);
    };

    stage(0, 0);                                // prologue: half-window 0

    const float s = 1.0f / (float)KSIZE;
    float* outp = out + (long)(b * CHUNKS_PER_BATCH + c0) * ROW;
    float4 prev = make_float4(0.f, 0.f, 0.f, 0.f);

    for (int j = 0; j <= gc; ++j) {             // gc+1 half-windows
        if (j < gc) stage((j + 1) & 1, j + 1);  // prefetch next (in flight
                                                // across the drain below)
        __syncthreads();                        // vmcnt(0): buf[j&1] ready

        // Sum 16 rows of the staged half-window; thread t owns float4 col t.
        const float4* __restrict__ B = buf[j & 1];
        float4 a0 = make_float4(0.f, 0.f, 0.f, 0.f);
        float4 a1 = make_float4(0.f, 0.f, 0.f, 0.f);
        #pragma unroll
        for (int r = 0; r < KSTRIDE; r += 2) {
            float4 u = B[r * ROW4 + t];
            float4 v = B[(r + 1) * ROW4 + t];
            a0.x += u.x; a0.y += u.y; a0.z += u.z; a0.w += u.w;
            a1.x += v.x; a1.y += v.y; a1.z += v.z; a1.w += v.w;
        }
        float4 cur = make_float4(a0.x + a1.x, a0.y + a1.y,
                                 a0.z + a1.z, a0.w + a1.w);

        if (j > 0) {
            float4 r = make_float4((prev.x + cur.x) * s,
                                   (prev.y + cur.y) * s,
                                   (prev.z + cur.z) * s,
                                   (prev.w + cur.w) * s);
            ((float4*)(outp + (long)(j - 1) * ROW))[t] = r;
        }
        prev = cur;

        __syncthreads();  // all reads of buf[(j+1)&1] done before next
                          // iteration's stage overwrites it (vmcnt already 0)
    }

    // Fused cu_comp tail write (fp32 representation in the flat out buffer).
    if (blk == 0 && t == 0) {
        int run = 0;
        tail[0] = 0.0f;
        #pragma unroll
        for (int i = 0; i < BATCH; ++i) {
            const int len = cu_seqlens[i + 1] - cu_seqlens[i];
            const int n = (len >= KSIZE) ? (len - KSIZE) / KSTRIDE + 1 : 0;
            run += n;
            tail[i + 1] = (float)run;
        }
    }
}

extern "C" void kernel_launch(void* const* d_in, const int* in_sizes, int n_in,
                              void* d_out, int out_size, void* d_ws, size_t ws_size,
                              hipStream_t stream) {
    const float* k          = (const float*)d_in[0];
    const int*   cu_seqlens = (const int*)d_in[1];
    float*       out        = (float*)d_out;
    float*       tail       = out + (long)TOTAL_CHUNKS * ROW;

    compress_k_fused<<<TOTAL_BLOCKS, 128, 0, stream>>>(k, cu_seqlens, out, tail);
}